// Round 9
// baseline (497.689 us; speedup 1.0000x reference)
//
#include <hip/hip_runtime.h>
#include <math.h>

typedef float f32x4 __attribute__((ext_vector_type(4)));
typedef short bf16x8 __attribute__((ext_vector_type(8)));
typedef unsigned int u32;
typedef unsigned short u16;

#define SPLITS 2

__device__ __forceinline__ u16 f2b(float x) {      // f32 -> bf16 RNE
    union { float f; u32 u; } v; v.f = x;
    return (u16)((v.u + 0x7FFFu + ((v.u >> 16) & 1u)) >> 16);
}

// Build: normalized bf16 tables (K-hat/Q-hat role, rinv folded in) and
// TRANSPOSED raw bf16 tables (V role, contiguous-kvcol fragments).
// Pad rows/cols to multiples of 64 with zeros.
__global__ __launch_bounds__(256) void prep_kernel(
    const float* __restrict__ users, const float* __restrict__ items,
    u16* __restrict__ uhat, u16* __restrict__ ihat,
    u16* __restrict__ uT,   u16* __restrict__ iT,
    int U, int I, int Upad, int Ipad)
{
    int lane = threadIdx.x & 63;
    int row  = (blockIdx.x << 2) + (threadIdx.x >> 6);
    const float* src; u16 *hat, *Tt; int N, Npad, r;
    if (row < Upad) { r = row; src = users; hat = uhat; Tt = uT; N = U; Npad = Upad; }
    else { r = row - Upad; if (r >= Ipad) return;
           src = items; hat = ihat; Tt = iT; N = I; Npad = Ipad; }
    float x = (r < N) ? src[(size_t)r * 64 + lane] : 0.0f;
    float s = x * x;
#pragma unroll
    for (int off = 32; off; off >>= 1) s += __shfl_xor(s, off, 64);
    float rinv = 1.0f / fmaxf(sqrtf(s), 1e-12f);
    hat[(size_t)r * 64 + lane] = f2b(x * rinv);          // x=0 pad -> 0
    Tt[(size_t)lane * Npad + r] = f2b(x);
}

// Dense flash-style masked softmax attention, one direction+split per block-4th.
// Per wave: 16 q-rows x 64-kvcol strip per iteration.
//  QK^T swapped: S^T = mfma(Khat, Qhat) -> lane holds qrow = lane&15 (matches
//  adj dwordx4 loads element-exact). w = (adj!=0 && s!=0) ? exp(s-1) : 0
//  (cosine <= 1 -> fixed max). P -> bf16 via per-wave LDS tile (A-layout reads).
//  PV: O^T = mfma(V^T, P^T) with V^T fragments straight from the transposed
//  raw table (contiguous 16B global loads). adj prefetched 1 tile ahead,
//  issued AFTER frag loads so per-use vmcnt keeps it in flight. No barriers.
__global__ __launch_bounds__(256, 2) void attn_kernel(
    const u16* __restrict__ uhat, const u16* __restrict__ ihat,
    const u16* __restrict__ uT,   const u16* __restrict__ iT,
    const float* __restrict__ adjU, const float* __restrict__ adjI,
    float* __restrict__ wsO, float* __restrict__ wsDen,
    int U, int I, int Upad, int Ipad, int nbU, int nbI)
{
    __shared__ u16 Plds[4][16][72];   // per-wave P tile, padded row stride

    const int lane = threadIdx.x & 63;
    const int wid  = threadIdx.x >> 6;
    const int r15  = lane & 15;
    const int g    = lane >> 4;
    const int T    = U + I;

    const int nbT = nbU + nbI;
    const int s   = blockIdx.x / nbT;
    const int b   = blockIdx.x % nbT;
    const int dir = (b >= nbU);

    int N, M, Mpad, rowoff, qg;
    const u16 *qh, *kh, *vt;
    const float* adj;
    if (!dir) { N=U; M=I; Mpad=Ipad; qh=uhat; kh=ihat; vt=iT; adj=adjU; rowoff=0; qg = b*4 + wid; }
    else      { N=I; M=U; Mpad=Upad; qh=ihat; kh=uhat; vt=uT; adj=adjI; rowoff=U; qg = (b-nbU)*4 + wid; }
    const int qbase = qg << 4;
    if (qbase >= N) return;           // safe: no barriers in this kernel

    const int ntiles = (M + 63) >> 6;
    const int t0 = (s * ntiles) / SPLITS, t1 = ((s + 1) * ntiles) / SPLITS;

    // loop-invariant Q-hat fragments: B[k][n], lane: col=r15(qrow), k=g*8+e
    const u16* qrowp = qh + (size_t)(qbase + r15) * 64 + g * 8;
    bf16x8 qf0 = *(const bf16x8*)(qrowp);
    bf16x8 qf1 = *(const bf16x8*)(qrowp + 32);

    const f32x4 zero4 = (f32x4){0.f, 0.f, 0.f, 0.f};
    f32x4 oacc[4];
#pragma unroll
    for (int d = 0; d < 4; ++d) oacc[d] = zero4;
    float wsum = 0.f;

    const float* adjrow = adj + (size_t)(qbase + r15) * M;

    f32x4 adjc[4];                    // prefetched adj for tile t
    {
        int tb = t0 << 6;
#pragma unroll
        for (int c = 0; c < 4; ++c) {
            int cb = tb + c * 16;
            adjc[c] = (cb < M) ? __builtin_nontemporal_load((const f32x4*)(adjrow + cb + g*4))
                               : zero4;
        }
    }

    for (int t = t0; t < t1; ++t) {
        const int tb = t << 6;
        // K-hat fragments (issued first): A[m][k], lane: row=r15(kvcol), k=g*8+e
        bf16x8 kf[4][2];
        bool cv[4];
#pragma unroll
        for (int c = 0; c < 4; ++c) {
            int cb = tb + c * 16;
            cv[c] = (cb < M);
            if (cv[c]) {
                const u16* kp = kh + (size_t)(cb + r15) * 64 + g * 8;
                kf[c][0] = *(const bf16x8*)(kp);
                kf[c][1] = *(const bf16x8*)(kp + 32);
            }
        }
        // V^T fragments: A2[m=dim][k=kvcol], lane: row=r15(dim), k=g*8+e
        bf16x8 vf[4][2];
#pragma unroll
        for (int d = 0; d < 4; ++d) {
            const u16* vp = vt + (size_t)(d * 16 + r15) * Mpad + tb + g * 8;
            vf[d][0] = *(const bf16x8*)(vp);
            vf[d][1] = *(const bf16x8*)(vp + 32);
        }
        // adj prefetch for t+1 (issued last -> stays in flight across compute)
        f32x4 adjn[4];
        {
            int tn = (t + 1 < t1) ? t + 1 : t;
            int tb2 = tn << 6;
#pragma unroll
            for (int c = 0; c < 4; ++c) {
                int cb = tb2 + c * 16;
                adjn[c] = (cb < M) ? __builtin_nontemporal_load((const f32x4*)(adjrow + cb + g*4))
                                   : zero4;
            }
        }

        // S^T = Khat · Qhat^T -> lane: qrow=r15, kvcol = 16c + g*4 + j
        u32* prow = (u32*)(&Plds[wid][r15][0]);
#pragma unroll
        for (int c = 0; c < 4; ++c) {
            u32 lo = 0, hi = 0;
            if (cv[c]) {
                f32x4 sa = __builtin_amdgcn_mfma_f32_16x16x32_bf16(kf[c][0], qf0, zero4, 0, 0, 0);
                sa = __builtin_amdgcn_mfma_f32_16x16x32_bf16(kf[c][1], qf1, sa, 0, 0, 0);
                float w0, w1, w2, w3;
#pragma unroll
                for (int j = 0; j < 4; ++j) {
                    float sv = sa[j], av = adjc[c][j];
                    float e  = __expf(sv - 1.0f);
                    float wj = (av != 0.0f && sv != 0.0f) ? e : 0.0f;
                    wsum += wj;
                    if (j == 0) w0 = wj; else if (j == 1) w1 = wj;
                    else if (j == 2) w2 = wj; else w3 = wj;
                }
                lo = (u32)f2b(w0) | ((u32)f2b(w1) << 16);
                hi = (u32)f2b(w2) | ((u32)f2b(w3) << 16);
            }
            prow[c * 8 + g * 2]     = lo;   // also zeroes OOB cols for PV
            prow[c * 8 + g * 2 + 1] = hi;
        }

        // P^T fragments: B2[k=kvcol][n=qrow], lane: col=r15, k=g*8+e (+32)
        bf16x8 pf0 = *(const bf16x8*)(&Plds[wid][r15][g * 8]);
        bf16x8 pf1 = *(const bf16x8*)(&Plds[wid][r15][32 + g * 8]);
#pragma unroll
        for (int d = 0; d < 4; ++d) {
            oacc[d] = __builtin_amdgcn_mfma_f32_16x16x32_bf16(vf[d][0], pf0, oacc[d], 0, 0, 0);
            oacc[d] = __builtin_amdgcn_mfma_f32_16x16x32_bf16(vf[d][1], pf1, oacc[d], 0, 0, 0);
        }
#pragma unroll
        for (int c = 0; c < 4; ++c) adjc[c] = adjn[c];
    }

    // den: lanes {l, l^16, l^32, l^48} share qrow=r15 -> 2-stage reduce
    wsum += __shfl_xor(wsum, 16, 64);
    wsum += __shfl_xor(wsum, 32, 64);

    if (lane < 16)
        wsDen[(size_t)s * T + rowoff + qbase + lane] = wsum;

    // O^T layout: col=r15(qrow), row = dim = d*16 + g*4 + j
    float* obase = wsO + ((size_t)s * T + rowoff + qbase + r15) * 64;
#pragma unroll
    for (int d = 0; d < 4; ++d)
#pragma unroll
        for (int j = 0; j < 4; ++j)
            obase[d * 16 + g * 4 + j] = oacc[d][j];
}

__global__ __launch_bounds__(256) void combine_kernel(
    const float* __restrict__ wsO, const float* __restrict__ wsDen,
    const float* __restrict__ users, const float* __restrict__ items,
    float* __restrict__ outU, float* __restrict__ outI, int U, int I)
{
    int lane = threadIdx.x & 63;
    int row  = (blockIdx.x << 2) + (threadIdx.x >> 6);
    int T = U + I;
    if (row >= T) return;
    float den = 0.f, o = 0.f;
#pragma unroll
    for (int s = 0; s < SPLITS; ++s) {
        den += wsDen[(size_t)s * T + row];
        o   += wsO[((size_t)s * T + row) * 64 + lane];
    }
    float* outp = (row < U) ? (outU + (size_t)row * 64) : (outI + (size_t)(row - U) * 64);
    if (den > 0.f) {
        outp[lane] = o / den;
    } else {
        // all entries masked: uniform softmax -> column mean of RAW kv table
        const float* kv = (row < U) ? items : users;
        int M = (row < U) ? I : U;
        float m = 0.f;
        for (int r = 0; r < M; ++r) m += kv[(size_t)r * 64 + lane];
        outp[lane] = m / (float)M;
    }
}

extern "C" void kernel_launch(void* const* d_in, const int* in_sizes, int n_in,
                              void* d_out, int out_size, void* d_ws, size_t ws_size,
                              hipStream_t stream) {
    const float* users = (const float*)d_in[2];
    const float* items = (const float*)d_in[3];
    const float* adjU  = (const float*)d_in[4];
    const float* adjI  = (const float*)d_in[5];
    const int U = in_sizes[2] / 64;
    const int I = in_sizes[3] / 64;
    const int Upad = (U + 63) & ~63;
    const int Ipad = (I + 63) & ~63;
    const int T = U + I;

    char* w = (char*)d_ws;
    u16* uhat = (u16*)w;  w += (size_t)Upad * 64 * 2;
    u16* ihat = (u16*)w;  w += (size_t)Ipad * 64 * 2;
    u16* uT   = (u16*)w;  w += (size_t)Upad * 64 * 2;
    u16* iT   = (u16*)w;  w += (size_t)Ipad * 64 * 2;
    float* wsO   = (float*)w;  w += (size_t)SPLITS * T * 64 * sizeof(float);
    float* wsDen = (float*)w;

    float* out  = (float*)d_out;
    float* outU = out + (size_t)T * 64;
    float* outI = outU + (size_t)U * 64;

    // passthrough outputs 0,1
    hipMemcpyAsync(out, users, (size_t)U * 64 * sizeof(float),
                   hipMemcpyDeviceToDevice, stream);
    hipMemcpyAsync(out + (size_t)U * 64, items, (size_t)I * 64 * sizeof(float),
                   hipMemcpyDeviceToDevice, stream);

    int prows = Upad + Ipad;
    prep_kernel<<<(prows + 3) / 4, 256, 0, stream>>>(users, items, uhat, ihat,
                                                     uT, iT, U, I, Upad, Ipad);

    int nbU = ((U + 15) / 16 + 3) / 4;
    int nbI = ((I + 15) / 16 + 3) / 4;
    attn_kernel<<<SPLITS * (nbU + nbI), 256, 0, stream>>>(
        uhat, ihat, uT, iT, adjU, adjI, wsO, wsDen, U, I, Upad, Ipad, nbU, nbI);

    combine_kernel<<<(T + 3) / 4, 256, 0, stream>>>(wsO, wsDen, users, items,
                                                    outU, outI, U, I);
}

// Round 10
// 398.012 us; speedup vs baseline: 1.2504x; 1.2504x over previous
//
#include <hip/hip_runtime.h>
#include <math.h>

typedef float f32x4 __attribute__((ext_vector_type(4)));
typedef short bf16x8 __attribute__((ext_vector_type(8)));
typedef unsigned int u32;
typedef unsigned short u16;

#define MAXSPLITS 8

__device__ __forceinline__ u16 f2b(float x) {      // f32 -> bf16 RNE
    union { float f; u32 u; } v; v.f = x;
    return (u16)((v.u + 0x7FFFu + ((v.u >> 16) & 1u)) >> 16);
}

// Build: normalized bf16 tables (K-hat/Q-hat role, rinv folded in) and
// TRANSPOSED raw bf16 tables (V role, contiguous-kvcol fragments).
// Pad rows/cols to multiples of 64 with zeros.
__global__ __launch_bounds__(256) void prep_kernel(
    const float* __restrict__ users, const float* __restrict__ items,
    u16* __restrict__ uhat, u16* __restrict__ ihat,
    u16* __restrict__ uT,   u16* __restrict__ iT,
    int U, int I, int Upad, int Ipad)
{
    int lane = threadIdx.x & 63;
    int row  = (blockIdx.x << 2) + (threadIdx.x >> 6);
    const float* src; u16 *hat, *Tt; int N, Npad, r;
    if (row < Upad) { r = row; src = users; hat = uhat; Tt = uT; N = U; Npad = Upad; }
    else { r = row - Upad; if (r >= Ipad) return;
           src = items; hat = ihat; Tt = iT; N = I; Npad = Ipad; }
    float x = (r < N) ? src[(size_t)r * 64 + lane] : 0.0f;
    float s = x * x;
#pragma unroll
    for (int off = 32; off; off >>= 1) s += __shfl_xor(s, off, 64);
    float rinv = 1.0f / fmaxf(sqrtf(s), 1e-12f);
    hat[(size_t)r * 64 + lane] = f2b(x * rinv);          // x=0 pad -> 0
    Tt[(size_t)lane * Npad + r] = f2b(x);
}

// Dense flash-style masked softmax attention.
// Per wave: 16 q-rows x 64-kvcol strip per iteration, K-range split S ways.
//  QK^T swapped: S^T = mfma(Khat, Qhat) -> lane holds qrow = lane&15 (matches
//  adj dwordx4 loads element-exact). w = (adj!=0 && s!=0) ? exp(s-1) : 0
//  (cosine <= 1 -> fixed max). P -> bf16 via per-wave LDS tile (A-layout reads).
//  PV: O^T = mfma(V^T, P^T) with V^T fragments straight from the transposed
//  raw table (contiguous 16B global loads). adj prefetched 1 tile ahead,
//  issued AFTER frag loads so per-use vmcnt keeps it in flight. No barriers.
__global__ __launch_bounds__(256, 2) void attn_kernel(
    const u16* __restrict__ uhat, const u16* __restrict__ ihat,
    const u16* __restrict__ uT,   const u16* __restrict__ iT,
    const float* __restrict__ adjU, const float* __restrict__ adjI,
    float* __restrict__ wsO, float* __restrict__ wsDen,
    int U, int I, int Upad, int Ipad, int nbU, int nbI, int S)
{
    __shared__ u16 Plds[4][16][72];   // per-wave P tile, padded row stride

    const int lane = threadIdx.x & 63;
    const int wid  = threadIdx.x >> 6;
    const int r15  = lane & 15;
    const int g    = lane >> 4;
    const int T    = U + I;

    const int nbT = nbU + nbI;
    const int s   = blockIdx.x / nbT;
    const int b   = blockIdx.x % nbT;
    const int dir = (b >= nbU);

    int N, M, Mpad, rowoff, qg;
    const u16 *qh, *kh, *vt;
    const float* adj;
    if (!dir) { N=U; M=I; Mpad=Ipad; qh=uhat; kh=ihat; vt=iT; adj=adjU; rowoff=0; qg = b*4 + wid; }
    else      { N=I; M=U; Mpad=Upad; qh=ihat; kh=uhat; vt=uT; adj=adjI; rowoff=U; qg = (b-nbU)*4 + wid; }
    const int qbase = qg << 4;
    if (qbase >= N) return;           // safe: no barriers in this kernel

    const int ntiles = (M + 63) >> 6;
    const int t0 = (s * ntiles) / S, t1 = ((s + 1) * ntiles) / S;

    // loop-invariant Q-hat fragments: B[k][n], lane: col=r15(qrow), k=g*8+e
    const u16* qrowp = qh + (size_t)(qbase + r15) * 64 + g * 8;
    bf16x8 qf0 = *(const bf16x8*)(qrowp);
    bf16x8 qf1 = *(const bf16x8*)(qrowp + 32);

    const f32x4 zero4 = (f32x4){0.f, 0.f, 0.f, 0.f};
    f32x4 oacc[4];
#pragma unroll
    for (int d = 0; d < 4; ++d) oacc[d] = zero4;
    float wsum = 0.f;

    const float* adjrow = adj + (size_t)(qbase + r15) * M;

    f32x4 adjc[4];                    // prefetched adj for tile t
    {
        int tb = t0 << 6;
#pragma unroll
        for (int c = 0; c < 4; ++c) {
            int cb = tb + c * 16;
            adjc[c] = (cb < M) ? __builtin_nontemporal_load((const f32x4*)(adjrow + cb + g*4))
                               : zero4;
        }
    }

    for (int t = t0; t < t1; ++t) {
        const int tb = t << 6;
        // K-hat fragments (issued first): A[m][k], lane: row=r15(kvcol), k=g*8+e
        bf16x8 kf[4][2];
        bool cv[4];
#pragma unroll
        for (int c = 0; c < 4; ++c) {
            int cb = tb + c * 16;
            cv[c] = (cb < M);
            if (cv[c]) {
                const u16* kp = kh + (size_t)(cb + r15) * 64 + g * 8;
                kf[c][0] = *(const bf16x8*)(kp);
                kf[c][1] = *(const bf16x8*)(kp + 32);
            }
        }
        // V^T fragments: A2[m=dim][k=kvcol], lane: row=r15(dim), k=g*8+e
        bf16x8 vf[4][2];
#pragma unroll
        for (int d = 0; d < 4; ++d) {
            const u16* vp = vt + (size_t)(d * 16 + r15) * Mpad + tb + g * 8;
            vf[d][0] = *(const bf16x8*)(vp);
            vf[d][1] = *(const bf16x8*)(vp + 32);
        }
        // adj prefetch for t+1 (issued last -> stays in flight across compute)
        f32x4 adjn[4];
        {
            int tn = (t + 1 < t1) ? t + 1 : t;
            int tb2 = tn << 6;
#pragma unroll
            for (int c = 0; c < 4; ++c) {
                int cb = tb2 + c * 16;
                adjn[c] = (cb < M) ? __builtin_nontemporal_load((const f32x4*)(adjrow + cb + g*4))
                                   : zero4;
            }
        }

        // S^T = Khat · Qhat^T -> lane: qrow=r15, kvcol = 16c + g*4 + j
        u32* prow = (u32*)(&Plds[wid][r15][0]);
#pragma unroll
        for (int c = 0; c < 4; ++c) {
            u32 lo = 0, hi = 0;
            if (cv[c]) {
                f32x4 sa = __builtin_amdgcn_mfma_f32_16x16x32_bf16(kf[c][0], qf0, zero4, 0, 0, 0);
                sa = __builtin_amdgcn_mfma_f32_16x16x32_bf16(kf[c][1], qf1, sa, 0, 0, 0);
                float w0, w1, w2, w3;
#pragma unroll
                for (int j = 0; j < 4; ++j) {
                    float sv = sa[j], av = adjc[c][j];
                    float e  = __expf(sv - 1.0f);
                    float wj = (av != 0.0f && sv != 0.0f) ? e : 0.0f;
                    wsum += wj;
                    if (j == 0) w0 = wj; else if (j == 1) w1 = wj;
                    else if (j == 2) w2 = wj; else w3 = wj;
                }
                lo = (u32)f2b(w0) | ((u32)f2b(w1) << 16);
                hi = (u32)f2b(w2) | ((u32)f2b(w3) << 16);
            }
            prow[c * 8 + g * 2]     = lo;   // also zeroes OOB cols for PV
            prow[c * 8 + g * 2 + 1] = hi;
        }

        // P^T fragments: B2[k=kvcol][n=qrow], lane: col=r15, k=g*8+e (+32)
        bf16x8 pf0 = *(const bf16x8*)(&Plds[wid][r15][g * 8]);
        bf16x8 pf1 = *(const bf16x8*)(&Plds[wid][r15][32 + g * 8]);
#pragma unroll
        for (int d = 0; d < 4; ++d) {
            oacc[d] = __builtin_amdgcn_mfma_f32_16x16x32_bf16(vf[d][0], pf0, oacc[d], 0, 0, 0);
            oacc[d] = __builtin_amdgcn_mfma_f32_16x16x32_bf16(vf[d][1], pf1, oacc[d], 0, 0, 0);
        }
#pragma unroll
        for (int c = 0; c < 4; ++c) adjc[c] = adjn[c];
    }

    // den: lanes {l, l^16, l^32, l^48} share qrow=r15 -> 2-stage reduce
    wsum += __shfl_xor(wsum, 16, 64);
    wsum += __shfl_xor(wsum, 32, 64);

    if (lane < 16)
        wsDen[(size_t)s * T + rowoff + qbase + lane] = wsum;

    // O^T layout: col=r15(qrow), row = dim = d*16 + g*4 + j -> f32x4 stores
    float* obase = wsO + ((size_t)s * T + rowoff + qbase + r15) * 64;
#pragma unroll
    for (int d = 0; d < 4; ++d)
        ((f32x4*)obase)[d * 4 + g] = oacc[d];
}

__global__ __launch_bounds__(256) void combine_kernel(
    const float* __restrict__ wsO, const float* __restrict__ wsDen,
    const float* __restrict__ users, const float* __restrict__ items,
    float* __restrict__ outU, float* __restrict__ outI, int U, int I, int S)
{
    int lane = threadIdx.x & 63;
    int row  = (blockIdx.x << 2) + (threadIdx.x >> 6);
    int T = U + I;
    if (row >= T) return;
    float den = 0.f, o = 0.f;
    for (int s = 0; s < S; ++s) {
        den += wsDen[(size_t)s * T + row];
        o   += wsO[((size_t)s * T + row) * 64 + lane];
    }
    float* outp = (row < U) ? (outU + (size_t)row * 64) : (outI + (size_t)(row - U) * 64);
    if (den > 0.f) {
        outp[lane] = o / den;
    } else {
        // all entries masked: uniform softmax -> column mean of RAW kv table
        const float* kv = (row < U) ? items : users;
        int M = (row < U) ? I : U;
        float m = 0.f;
        for (int r = 0; r < M; ++r) m += kv[(size_t)r * 64 + lane];
        outp[lane] = m / (float)M;
    }
}

extern "C" void kernel_launch(void* const* d_in, const int* in_sizes, int n_in,
                              void* d_out, int out_size, void* d_ws, size_t ws_size,
                              hipStream_t stream) {
    const float* users = (const float*)d_in[2];
    const float* items = (const float*)d_in[3];
    const float* adjU  = (const float*)d_in[4];
    const float* adjI  = (const float*)d_in[5];
    const int U = in_sizes[2] / 64;
    const int I = in_sizes[3] / 64;
    const int Upad = (U + 63) & ~63;
    const int Ipad = (I + 63) & ~63;
    const int T = U + I;

    // Pick the K-range split count from available scratch (deterministic:
    // depends only on ws_size). Round 9 proved ws_size >= 14.3 MB -> S >= 2.
    const size_t tables_b   = (size_t)(Upad + Ipad) * 64 * 2 * 2;  // hat + T, u16
    const size_t per_split_b = (size_t)T * 64 * sizeof(float) + (size_t)T * sizeof(float);
    int S = 1;
    if (ws_size > tables_b)
        S = (int)((ws_size - tables_b) / per_split_b);
    if (S < 1) S = 1;
    if (S > MAXSPLITS) S = MAXSPLITS;

    char* w = (char*)d_ws;
    u16* uhat = (u16*)w;  w += (size_t)Upad * 64 * 2;
    u16* ihat = (u16*)w;  w += (size_t)Ipad * 64 * 2;
    u16* uT   = (u16*)w;  w += (size_t)Upad * 64 * 2;
    u16* iT   = (u16*)w;  w += (size_t)Ipad * 64 * 2;
    float* wsO   = (float*)w;  w += (size_t)S * T * 64 * sizeof(float);
    float* wsDen = (float*)w;

    float* out  = (float*)d_out;
    float* outU = out + (size_t)T * 64;
    float* outI = outU + (size_t)U * 64;

    // passthrough outputs 0,1
    hipMemcpyAsync(out, users, (size_t)U * 64 * sizeof(float),
                   hipMemcpyDeviceToDevice, stream);
    hipMemcpyAsync(out + (size_t)U * 64, items, (size_t)I * 64 * sizeof(float),
                   hipMemcpyDeviceToDevice, stream);

    int prows = Upad + Ipad;
    prep_kernel<<<(prows + 3) / 4, 256, 0, stream>>>(users, items, uhat, ihat,
                                                     uT, iT, U, I, Upad, Ipad);

    int nbU = ((U + 15) / 16 + 3) / 4;
    int nbI = ((I + 15) / 16 + 3) / 4;
    attn_kernel<<<S * (nbU + nbI), 256, 0, stream>>>(
        uhat, ihat, uT, iT, adjU, adjI, wsO, wsDen, U, I, Upad, Ipad, nbU, nbI, S);

    combine_kernel<<<(T + 3) / 4, 256, 0, stream>>>(wsO, wsDen, users, items,
                                                    outU, outI, U, I, S);
}